// Round 18
// baseline (57.843 us; speedup 1.0000x reference)
//
#include <hip/hip_runtime.h>

#define N_NODES 1024
#define BATCH   128
#define E_DIM   16

// S / xbt panel format (bf16, per 128-row x 1024-k panel, 256KB):
//   elem(row, k) at (k>>6)*8192 + ((k>>3)&7)*1024 + row*8 + (k&7)
// Wt per-node tiled: n*4096 + kblk*512 + o*8 + e   (i = kblk*8+e)
// xg layout (node-major, swizzled): short off =
//   node*8192 + b*64 + ((ib ^ (b&7))*8 + e)   where i = ib*8+e

typedef __attribute__((ext_vector_type(8))) short bf16x8;
typedef __attribute__((ext_vector_type(4))) float f32x4;
typedef __attribute__((ext_vector_type(16))) float f32x16;

__device__ __forceinline__ unsigned short f2bf(float f) {
    union { float f; unsigned int u; } v; v.f = f;
    unsigned int u = v.u;
    u += 0x7FFFu + ((u >> 16) & 1u);
    return (unsigned short)(u >> 16);
}

__device__ __forceinline__ void gload_lds16(const void* g, void* l) {
    __builtin_amdgcn_global_load_lds(
        (const __attribute__((address_space(1))) unsigned int*)g,
        (__attribute__((address_space(3))) unsigned int*)l, 16, 0, 0);
}

// ---------------- P: fused producers (xt | weights-4node | supports) --------
__global__ __launch_bounds__(256) void k_prep2(const float* __restrict__ x,
                                               const float* __restrict__ emb,
                                               const float* __restrict__ wpool,
                                               const float* __restrict__ bpool,
                                               unsigned short* __restrict__ xbt,
                                               unsigned short* __restrict__ sup,
                                               unsigned short* __restrict__ Wt,
                                               float* __restrict__ bias) {
    __shared__ float sm[132];
    const int bid = blockIdx.x;
    const int t = threadIdx.x;

    if (bid < 2048) {
        const int b = bid >> 4, kt64 = bid & 15;
        unsigned short* dstp = xbt + (long)(b >> 1) * 131072 + kt64 * 8192
                             + (b & 1) * 512;
#pragma unroll
        for (int h = 0; h < 2; ++h) {
            const int g = h * 256 + t;
            const int kblk = g >> 6, c = g & 63;
            const float* s = x + ((long)b * 1024 + kt64 * 64 + kblk * 8) * 64 + c;
            bf16x8 r;
#pragma unroll
            for (int e = 0; e < 8; ++e) r[e] = (short)f2bf(s[e * 64]);
            *(bf16x8*)(dstp + kblk * 1024 + c * 8) = r;
        }
    } else if (bid < 2304) {
        float (*en4)[E_DIM] = (float(*)[E_DIM])sm;
        const int n0 = (bid - 2048) * 4;
        if (t < 64) en4[t >> 4][t & 15] = emb[(n0 + (t >> 4)) * E_DIM + (t & 15)];
        __syncthreads();
        const int o = t & 63;
#pragma unroll
        for (int p = 0; p < 2; ++p) {
            const int kblk = p * 4 + (t >> 6);
            float w[4][8];
#pragma unroll
            for (int nn = 0; nn < 4; ++nn)
#pragma unroll
                for (int e = 0; e < 8; ++e) w[nn][e] = 0.f;
            for (int ed = 0; ed < E_DIM; ++ed) {
                float v[8];
#pragma unroll
                for (int e = 0; e < 8; ++e)
                    v[e] = wpool[ed * 4096 + (kblk * 8 + e) * 64 + o];
#pragma unroll
                for (int nn = 0; nn < 4; ++nn)
#pragma unroll
                    for (int e = 0; e < 8; ++e)
                        w[nn][e] = fmaf(en4[nn][ed], v[e], w[nn][e]);
            }
#pragma unroll
            for (int nn = 0; nn < 4; ++nn) {
                bf16x8 r;
#pragma unroll
                for (int e = 0; e < 8; ++e) r[e] = (short)f2bf(w[nn][e]);
                *(bf16x8*)(Wt + (long)(n0 + nn) * 4096 + kblk * 512 + o * 8) = r;
            }
        }
        {
            const int nn = t >> 6, oo = t & 63;
            float s = 0.f;
#pragma unroll
            for (int e = 0; e < E_DIM; ++e) s = fmaf(en4[nn][e], bpool[e * 64 + oo], s);
            bias[(n0 + nn) * 64 + oo] = s;
        }
    } else {
        float* en  = sm;
        float* red = sm + 128;
        const int n = bid - 2304;
        if (t < E_DIM) en[t] = emb[n * E_DIM + t];
        __syncthreads();
        float sc[4];
        float mx = -1e30f;
#pragma unroll
        for (int r = 0; r < 4; ++r) {
            const float* em = &emb[(r * 256 + t) * E_DIM];
            float s = 0.f;
#pragma unroll
            for (int e = 0; e < E_DIM; ++e) s = fmaf(en[e], em[e], s);
            s = fmaxf(s, 0.f);
            sc[r] = s;
            mx = fmaxf(mx, s);
        }
#pragma unroll
        for (int o = 32; o > 0; o >>= 1) mx = fmaxf(mx, __shfl_xor(mx, o));
        if ((t & 63) == 0) red[t >> 6] = mx;
        __syncthreads();
        mx = fmaxf(fmaxf(red[0], red[1]), fmaxf(red[2], red[3]));
        float sum = 0.f;
#pragma unroll
        for (int r = 0; r < 4; ++r) { sc[r] = __expf(sc[r] - mx); sum += sc[r]; }
#pragma unroll
        for (int o = 32; o > 0; o >>= 1) sum += __shfl_xor(sum, o);
        __syncthreads();
        if ((t & 63) == 0) red[t >> 6] = sum;
        __syncthreads();
        sum = red[0] + red[1] + red[2] + red[3];
        const float inv = 1.f / sum;
#pragma unroll
        for (int r = 0; r < 4; ++r) {
            const int m = r * 256 + t;
            const int off = (n >> 7) * 131072 + (m >> 6) * 8192 + ((m >> 3) & 7) * 1024
                          + (n & 127) * 8 + (m & 7);
            sup[off] = f2bf(sc[r] * inv);
        }
    }
}

// ---------------- D: xg = S @ X, 128n x 256j block, wave 128x64 (acc[4][2]) -
// LDS/buffer 24KB: A [4 kblk][128 row][8] (8KB) | B [2 panel][4 kblk][128][8].
// 3 buffers (72KB), 1 barrier/iter, depth-2 prefetch, grid 256 blocks.
__global__ __launch_bounds__(256, 2) void k_agg(const unsigned short* __restrict__ S,
                                                const unsigned short* __restrict__ Bt,
                                                unsigned short* __restrict__ xg) {
    __shared__ __align__(16) char lds[73728];   // 3 x 24KB
    const int t = threadIdx.x;
    const int lane = t & 63, wid = t >> 6;      // wid = wave j-column 0..3

    const int hw   = blockIdx.x;                // grid 256
    const int work = (hw & 7) * 32 + (hw >> 3); // XCD-chunked swizzle
    const int n0 = (work & 7) * 128, j0 = (work >> 3) * 256;

    f32x16 acc[4][2];
#pragma unroll
    for (int m = 0; m < 4; ++m)
#pragma unroll
        for (int n = 0; n < 2; ++n)
#pragma unroll
            for (int r = 0; r < 16; ++r) acc[m][n][r] = 0.f;

    // 24 chunks of 1KB per K-tile (8 A + 16 B over 2 panels); wave owns 6
    const unsigned short* sp[6];
    int doff[6];
#pragma unroll
    for (int i = 0; i < 6; ++i) {
        const int c = wid * 6 + i;
        if (c < 8) {
            sp[i]   = S + (n0 >> 7) * 131072 + c * 512 + lane * 8;
            doff[i] = c * 1024;
        } else {
            const int cc = c - 8;               // 0..15: panel cc>>3, chunk cc&7
            sp[i]   = Bt + (long)((j0 >> 7) + (cc >> 3)) * 131072
                    + (cc & 7) * 512 + lane * 8;
            doff[i] = 8192 + cc * 1024;
        }
    }
#define STAGE(bufidx, kt) do {                                           \
        char* buf_ = lds + (bufidx) * 24576;                             \
        const int ko_ = (kt) * 4096;                                     \
        gload_lds16(sp[0] + ko_, buf_ + doff[0]);                        \
        gload_lds16(sp[1] + ko_, buf_ + doff[1]);                        \
        gload_lds16(sp[2] + ko_, buf_ + doff[2]);                        \
        gload_lds16(sp[3] + ko_, buf_ + doff[3]);                        \
        gload_lds16(sp[4] + ko_, buf_ + doff[4]);                        \
        gload_lds16(sp[5] + ko_, buf_ + doff[5]);                        \
    } while (0)

    // fragment offsets: kstep s gives kblk = s*2 + lh (stride 4096B per s)
    const int lh = lane >> 5, lr = lane & 31;
    int aoff[4], boff[2];
#pragma unroll
    for (int m = 0; m < 4; ++m)
        aoff[m] = lh * 2048 + (m * 32 + lr) * 16;
#pragma unroll
    for (int n = 0; n < 2; ++n) {
        const int jcol = wid * 64 + n * 32 + lr;          // 0..255
        boff[n] = 8192 + (jcol >> 7) * 8192 + lh * 2048 + (jcol & 127) * 16;
    }

    STAGE(0, 0); STAGE(1, 1);              // 12 loads/wave in flight
    int bcur = 0;
    for (int kt = 0; kt < 32; ++kt) {
        if (kt < 31) asm volatile("s_waitcnt vmcnt(6)" ::: "memory");
        else         asm volatile("s_waitcnt vmcnt(0)" ::: "memory");
        __builtin_amdgcn_s_barrier();
        asm volatile("" ::: "memory");
        __builtin_amdgcn_sched_barrier(0);
        const int bprev = (bcur + 2 >= 3) ? bcur - 1 : bcur + 2;
        if (kt + 2 < 32) STAGE(bprev, kt + 2);
        const char* cur = lds + bcur * 24576;
        __builtin_amdgcn_s_setprio(1);
#pragma unroll
        for (int s = 0; s < 2; ++s) {
            bf16x8 a[4], b[2];
#pragma unroll
            for (int m = 0; m < 4; ++m) a[m] = *(const bf16x8*)(cur + s * 4096 + aoff[m]);
#pragma unroll
            for (int n = 0; n < 2; ++n) b[n] = *(const bf16x8*)(cur + s * 4096 + boff[n]);
#pragma unroll
            for (int m = 0; m < 4; ++m)
#pragma unroll
                for (int n = 0; n < 2; ++n)
                    acc[m][n] = __builtin_amdgcn_mfma_f32_32x32x16_bf16(a[m], b[n], acc[m][n], 0, 0, 0);
        }
        __builtin_amdgcn_s_setprio(0);
        asm volatile("" ::: "memory");
        __builtin_amdgcn_sched_barrier(0);
        bcur = (bcur + 1 >= 3) ? 0 : bcur + 1;
    }
#undef STAGE
    __syncthreads();

    // 2-pass epilogue: each pass stages 128 rows x 128 cols bf16 -> xg
    char* lb = lds;
    const int b0base = j0 >> 6;
#pragma unroll
    for (int pass = 0; pass < 2; ++pass) {
        if ((wid >> 1) == pass) {
            const int colb = (wid & 1) * 64;
#pragma unroll
            for (int m = 0; m < 4; ++m) {
                const int rowb = m * 32 + 4 * lh;
#pragma unroll
                for (int n = 0; n < 2; ++n) {
                    const int col = colb + n * 32 + lr;
#pragma unroll
                    for (int r = 0; r < 16; ++r) {
                        const int row = rowb + (r & 3) + 8 * (r >> 2);
                        *(unsigned short*)(lb + row * 256 + ((col * 2) ^ ((row & 7) << 4))) =
                            f2bf(acc[m][n][r]);
                    }
                }
            }
        }
        __syncthreads();
#pragma unroll
        for (int i = 0; i < 8; ++i) {
            const int idx = i * 256 + t;
            const int row = idx >> 4, cc = idx & 15;
            bf16x8 v = *(const bf16x8*)(lb + row * 256 + ((cc * 16) ^ ((row & 7) << 4)));
            const int b = b0base + pass * 2 + (cc >> 3);
            const long dst = (long)(n0 + row) * 8192 + b * 64 + ((cc & 7) ^ (b & 7)) * 8;
            *(bf16x8*)(xg + dst) = v;
        }
        __syncthreads();
    }
}

// ---------------- E: out, 2 nodes/block, f32x4 staged stores (R17) ----------
__global__ __launch_bounds__(256) void k_out(const unsigned short* __restrict__ xg,
                                             const unsigned short* __restrict__ Wt,
                                             const float* __restrict__ bias,
                                             float* __restrict__ out) {
    __shared__ __align__(16) char lds[49152];
    const int t = threadIdx.x, lane = t & 63, wid = t >> 6;
    const int nb = blockIdx.x * 2;
#pragma unroll
    for (int i = 0; i < 12; ++i) {
        const int c = wid * 12 + i;
        if (c < 32) {
            const int nn = c >> 4, k = c & 15;
            gload_lds16(xg + (long)(nb + nn) * 8192 + k * 512 + lane * 8,
                        lds + nn * 16384 + k * 1024);
        } else {
            const int cc = c - 32, nn = cc >> 3, k = cc & 7;
            gload_lds16(Wt + (long)(nb + nn) * 4096 + k * 512 + lane * 8,
                        lds + 32768 + nn * 8192 + k * 1024);
        }
    }
    __syncthreads();

    const int ns   = wid >> 1;
    const int node = nb + ns;
    const int bh   = wid & 1;
    const char* xl  = lds + ns * 16384;
    const char* wlp = lds + 32768 + ns * 8192;
    const int p = lane & 15, q = lane >> 4;

    f32x4 acc[4][4];
#pragma unroll
    for (int m = 0; m < 4; ++m)
#pragma unroll
        for (int n = 0; n < 4; ++n) acc[m][n] = f32x4{0.f, 0.f, 0.f, 0.f};

#pragma unroll
    for (int s = 0; s < 2; ++s) {
        const int kb = s * 4 + q;
        bf16x8 a[4], b[4];
#pragma unroll
        for (int m = 0; m < 4; ++m) {
            const int brow = bh * 64 + m * 16 + p;
            a[m] = *(const bf16x8*)(xl + brow * 128 + ((kb ^ (lane & 7)) << 4));
        }
#pragma unroll
        for (int n = 0; n < 4; ++n)
            b[n] = *(const bf16x8*)(wlp + kb * 1024 + (n * 16 + p) * 16);
#pragma unroll
        for (int m = 0; m < 4; ++m)
#pragma unroll
            for (int n = 0; n < 4; ++n)
                acc[m][n] = __builtin_amdgcn_mfma_f32_16x16x32_bf16(a[m], b[n], acc[m][n], 0, 0, 0);
    }

    float bv[4];
#pragma unroll
    for (int n = 0; n < 4; ++n) bv[n] = bias[node * 64 + n * 16 + p];
    __syncthreads();

#pragma unroll
    for (int pass = 0; pass < 2; ++pass) {
        if (bh == pass) {
            char* tb = lds + ns * 17408;
#pragma unroll
            for (int m = 0; m < 4; ++m)
#pragma unroll
                for (int n = 0; n < 4; ++n)
#pragma unroll
                    for (int r = 0; r < 4; ++r) {
                        const int brow = m * 16 + q * 4 + r;
                        *(float*)(tb + brow * 272 + (n * 16 + p) * 4) =
                            acc[m][n][r] + bv[n];
                    }
        }
        __syncthreads();
#pragma unroll
        for (int i = 0; i < 8; ++i) {
            const int idx = i * 256 + t;
            const int tns = idx >> 10, rem = idx & 1023;
            const int b = rem >> 4, g = rem & 15;
            f32x4 v = *(const f32x4*)(lds + tns * 17408 + b * 272 + g * 16);
            *(f32x4*)(out + (long)(pass * 64 + b) * 65536 + (nb + tns) * 64 + g * 4) = v;
        }
        __syncthreads();
    }
}

extern "C" void kernel_launch(void* const* d_in, const int* in_sizes, int n_in,
                              void* d_out, int out_size, void* d_ws, size_t ws_size,
                              hipStream_t stream) {
    const float* x     = (const float*)d_in[0];
    const float* emb   = (const float*)d_in[1];
    const float* wpool = (const float*)d_in[2];
    const float* bpool = (const float*)d_in[3];
    float* out = (float*)d_out;

    char* ws = (char*)d_ws;
    unsigned short* sup  = (unsigned short*)(ws);                        // 2 MiB
    unsigned short* xbt  = (unsigned short*)(ws + (2u  << 20));          // 16 MiB
    unsigned short* Wt   = (unsigned short*)(ws + (18u << 20));          // 8 MiB
    float*          bias = (float*)         (ws + (26u << 20));          // 256 KiB
    unsigned short* xg   = (unsigned short*)(ws + (27u << 20));          // 16 MiB
    (void)in_sizes; (void)n_in; (void)out_size; (void)ws_size;

    k_prep2<<<dim3(3328), dim3(256), 0, stream>>>(x, emb, wpool, bpool,
                                                  xbt, sup, Wt, bias);
    k_agg<<<dim3(256), dim3(256), 0, stream>>>(sup, xbt, xg);
    k_out<<<dim3(512), dim3(256), 0, stream>>>(xg, Wt, bias, out);
}

// Round 19
// 56.601 us; speedup vs baseline: 1.0219x; 1.0219x over previous
//
#include <hip/hip_runtime.h>

#define N_NODES 1024
#define BATCH   128
#define E_DIM   16

// S / xbt panel format (bf16, per 128-row x 1024-k panel, 256KB):
//   elem(row, k) at (k>>6)*8192 + ((k>>3)&7)*1024 + row*8 + (k&7)
// Wt per-node tiled: n*4096 + kblk*512 + o*8 + e   (i = kblk*8+e)
// xg layout (node-major, swizzled): short off =
//   node*8192 + b*64 + ((ib ^ (b&7))*8 + e)   where i = ib*8+e

typedef __attribute__((ext_vector_type(8))) short bf16x8;
typedef __attribute__((ext_vector_type(4))) float f32x4;
typedef __attribute__((ext_vector_type(16))) float f32x16;

__device__ __forceinline__ unsigned short f2bf(float f) {
    union { float f; unsigned int u; } v; v.f = f;
    unsigned int u = v.u;
    u += 0x7FFFu + ((u >> 16) & 1u);
    return (unsigned short)(u >> 16);
}

__device__ __forceinline__ void gload_lds16(const void* g, void* l) {
    __builtin_amdgcn_global_load_lds(
        (const __attribute__((address_space(1))) unsigned int*)g,
        (__attribute__((address_space(3))) unsigned int*)l, 16, 0, 0);
}

// ---------------- P: fused producers (xt | weights-4node | supports) --------
__global__ __launch_bounds__(256) void k_prep2(const float* __restrict__ x,
                                               const float* __restrict__ emb,
                                               const float* __restrict__ wpool,
                                               const float* __restrict__ bpool,
                                               unsigned short* __restrict__ xbt,
                                               unsigned short* __restrict__ sup,
                                               unsigned short* __restrict__ Wt,
                                               float* __restrict__ bias) {
    __shared__ float sm[132];
    const int bid = blockIdx.x;
    const int t = threadIdx.x;

    if (bid < 2048) {
        const int b = bid >> 4, kt64 = bid & 15;
        unsigned short* dstp = xbt + (long)(b >> 1) * 131072 + kt64 * 8192
                             + (b & 1) * 512;
#pragma unroll
        for (int h = 0; h < 2; ++h) {
            const int g = h * 256 + t;
            const int kblk = g >> 6, c = g & 63;
            const float* s = x + ((long)b * 1024 + kt64 * 64 + kblk * 8) * 64 + c;
            bf16x8 r;
#pragma unroll
            for (int e = 0; e < 8; ++e) r[e] = (short)f2bf(s[e * 64]);
            *(bf16x8*)(dstp + kblk * 1024 + c * 8) = r;
        }
    } else if (bid < 2304) {
        float (*en4)[E_DIM] = (float(*)[E_DIM])sm;
        const int n0 = (bid - 2048) * 4;
        if (t < 64) en4[t >> 4][t & 15] = emb[(n0 + (t >> 4)) * E_DIM + (t & 15)];
        __syncthreads();
        const int o = t & 63;
#pragma unroll
        for (int p = 0; p < 2; ++p) {
            const int kblk = p * 4 + (t >> 6);
            float w[4][8];
#pragma unroll
            for (int nn = 0; nn < 4; ++nn)
#pragma unroll
                for (int e = 0; e < 8; ++e) w[nn][e] = 0.f;
            for (int ed = 0; ed < E_DIM; ++ed) {
                float v[8];
#pragma unroll
                for (int e = 0; e < 8; ++e)
                    v[e] = wpool[ed * 4096 + (kblk * 8 + e) * 64 + o];
#pragma unroll
                for (int nn = 0; nn < 4; ++nn)
#pragma unroll
                    for (int e = 0; e < 8; ++e)
                        w[nn][e] = fmaf(en4[nn][ed], v[e], w[nn][e]);
            }
#pragma unroll
            for (int nn = 0; nn < 4; ++nn) {
                bf16x8 r;
#pragma unroll
                for (int e = 0; e < 8; ++e) r[e] = (short)f2bf(w[nn][e]);
                *(bf16x8*)(Wt + (long)(n0 + nn) * 4096 + kblk * 512 + o * 8) = r;
            }
        }
        {
            const int nn = t >> 6, oo = t & 63;
            float s = 0.f;
#pragma unroll
            for (int e = 0; e < E_DIM; ++e) s = fmaf(en4[nn][e], bpool[e * 64 + oo], s);
            bias[(n0 + nn) * 64 + oo] = s;
        }
    } else {
        float* en  = sm;
        float* red = sm + 128;
        const int n = bid - 2304;
        if (t < E_DIM) en[t] = emb[n * E_DIM + t];
        __syncthreads();
        float sc[4];
        float mx = -1e30f;
#pragma unroll
        for (int r = 0; r < 4; ++r) {
            const float* em = &emb[(r * 256 + t) * E_DIM];
            float s = 0.f;
#pragma unroll
            for (int e = 0; e < E_DIM; ++e) s = fmaf(en[e], em[e], s);
            s = fmaxf(s, 0.f);
            sc[r] = s;
            mx = fmaxf(mx, s);
        }
#pragma unroll
        for (int o = 32; o > 0; o >>= 1) mx = fmaxf(mx, __shfl_xor(mx, o));
        if ((t & 63) == 0) red[t >> 6] = mx;
        __syncthreads();
        mx = fmaxf(fmaxf(red[0], red[1]), fmaxf(red[2], red[3]));
        float sum = 0.f;
#pragma unroll
        for (int r = 0; r < 4; ++r) { sc[r] = __expf(sc[r] - mx); sum += sc[r]; }
#pragma unroll
        for (int o = 32; o > 0; o >>= 1) sum += __shfl_xor(sum, o);
        __syncthreads();
        if ((t & 63) == 0) red[t >> 6] = sum;
        __syncthreads();
        sum = red[0] + red[1] + red[2] + red[3];
        const float inv = 1.f / sum;
#pragma unroll
        for (int r = 0; r < 4; ++r) {
            const int m = r * 256 + t;
            const int off = (n >> 7) * 131072 + (m >> 6) * 8192 + ((m >> 3) & 7) * 1024
                          + (n & 127) * 8 + (m & 7);
            sup[off] = f2bf(sc[r] * inv);
        }
    }
}

// ---------------- D: xg = S @ X, 256n x 128j block, 8 waves (64x64/wave) ----
// LDS/buffer 24KB: A [2 panel][4 kblk][128 row][8] (16KB) | B [4 kblk][128][8].
// 3 buffers (72KB), 1 barrier/iter, depth-2 prefetch, grid 256, 8 waves/CU.
__global__ __launch_bounds__(512, 2) void k_agg(const unsigned short* __restrict__ S,
                                                const unsigned short* __restrict__ Bt,
                                                unsigned short* __restrict__ xg) {
    __shared__ __align__(16) char lds[73728];   // 3 x 24KB
    const int t = threadIdx.x;
    const int lane = t & 63, wid = t >> 6;      // 8 waves
    const int wr = wid >> 1, wc = wid & 1;      // 4 n-rows x 2 j-cols

    const int hw   = blockIdx.x;                // grid 256
    const int work = (hw & 7) * 32 + (hw >> 3); // XCD-chunked swizzle
    const int n0 = (work & 3) * 256, j0 = (work >> 2) * 128;

    f32x16 acc[2][2];
#pragma unroll
    for (int m = 0; m < 2; ++m)
#pragma unroll
        for (int n = 0; n < 2; ++n)
#pragma unroll
            for (int r = 0; r < 16; ++r) acc[m][n][r] = 0.f;

    // 24 chunks of 1KB per K-tile (16 A over 2 panels + 8 B); wave owns 3
    const unsigned short* sp[3];
    int doff[3];
#pragma unroll
    for (int i = 0; i < 3; ++i) {
        const int c = wid * 3 + i;
        if (c < 16) {
            const int p = c >> 3, ch = c & 7;
            sp[i]   = S + (long)((n0 >> 7) + p) * 131072 + ch * 512 + lane * 8;
            doff[i] = p * 8192 + ch * 1024;
        } else {
            const int ch = c - 16;
            sp[i]   = Bt + (long)(j0 >> 7) * 131072 + ch * 512 + lane * 8;
            doff[i] = 16384 + ch * 1024;
        }
    }
#define STAGE(bufidx, kt) do {                                           \
        char* buf_ = lds + (bufidx) * 24576;                             \
        const int ko_ = (kt) * 4096;                                     \
        gload_lds16(sp[0] + ko_, buf_ + doff[0]);                        \
        gload_lds16(sp[1] + ko_, buf_ + doff[1]);                        \
        gload_lds16(sp[2] + ko_, buf_ + doff[2]);                        \
    } while (0)

    // fragment offsets: kstep s gives kblk = s*2 + lh (kblk stride 2048B)
    const int lh = lane >> 5, lr = lane & 31;
    int aoff[2], boff[2];
#pragma unroll
    for (int m = 0; m < 2; ++m) {
        const int row = wr * 64 + m * 32 + lr;            // 0..255
        aoff[m] = (row >> 7) * 8192 + lh * 2048 + (row & 127) * 16;
    }
#pragma unroll
    for (int n = 0; n < 2; ++n) {
        const int jcol = wc * 64 + n * 32 + lr;           // 0..127
        boff[n] = 16384 + lh * 2048 + jcol * 16;
    }

    STAGE(0, 0); STAGE(1, 1);              // 6 loads/wave in flight
    int bcur = 0;
    for (int kt = 0; kt < 32; ++kt) {
        if (kt < 31) asm volatile("s_waitcnt vmcnt(3)" ::: "memory");
        else         asm volatile("s_waitcnt vmcnt(0)" ::: "memory");
        __builtin_amdgcn_s_barrier();
        asm volatile("" ::: "memory");
        __builtin_amdgcn_sched_barrier(0);
        const int bprev = (bcur + 2 >= 3) ? bcur - 1 : bcur + 2;
        if (kt + 2 < 32) STAGE(bprev, kt + 2);
        const char* cur = lds + bcur * 24576;
        __builtin_amdgcn_s_setprio(1);
#pragma unroll
        for (int s = 0; s < 2; ++s) {
            bf16x8 a[2], b[2];
#pragma unroll
            for (int m = 0; m < 2; ++m) a[m] = *(const bf16x8*)(cur + s * 4096 + aoff[m]);
#pragma unroll
            for (int n = 0; n < 2; ++n) b[n] = *(const bf16x8*)(cur + s * 4096 + boff[n]);
#pragma unroll
            for (int m = 0; m < 2; ++m)
#pragma unroll
                for (int n = 0; n < 2; ++n)
                    acc[m][n] = __builtin_amdgcn_mfma_f32_32x32x16_bf16(a[m], b[n], acc[m][n], 0, 0, 0);
        }
        __builtin_amdgcn_s_setprio(0);
        asm volatile("" ::: "memory");
        __builtin_amdgcn_sched_barrier(0);
        bcur = (bcur + 1 >= 3) ? 0 : bcur + 1;
    }
#undef STAGE
    __syncthreads();

    // epilogue: acc -> LDS bf16 [256 row][128 col] swizzled (64KB) -> xg
    char* lb = lds;
#pragma unroll
    for (int m = 0; m < 2; ++m) {
        const int rowb = wr * 64 + m * 32 + 4 * lh;
#pragma unroll
        for (int n = 0; n < 2; ++n) {
            const int col = wc * 64 + n * 32 + lr;
#pragma unroll
            for (int r = 0; r < 16; ++r) {
                const int row = rowb + (r & 3) + 8 * (r >> 2);
                *(unsigned short*)(lb + row * 256 + ((col * 2) ^ ((row & 7) << 4))) =
                    f2bf(acc[m][n][r]);
            }
        }
    }
    __syncthreads();
    const int b0 = j0 >> 6;
#pragma unroll
    for (int i = 0; i < 8; ++i) {
        const int idx = i * 512 + t;          // 4096 granules of 16B
        const int row = idx >> 4, cc = idx & 15;
        bf16x8 v = *(const bf16x8*)(lb + row * 256 + ((cc * 16) ^ ((row & 7) << 4)));
        const int b = b0 + (cc >> 3);
        const long dst = (long)(n0 + row) * 8192 + b * 64 + ((cc & 7) ^ (b & 7)) * 8;
        *(bf16x8*)(xg + dst) = v;
    }
}

// ---------------- E: out, 2 nodes/block, f32x4 staged stores (R17) ----------
__global__ __launch_bounds__(256) void k_out(const unsigned short* __restrict__ xg,
                                             const unsigned short* __restrict__ Wt,
                                             const float* __restrict__ bias,
                                             float* __restrict__ out) {
    __shared__ __align__(16) char lds[49152];
    const int t = threadIdx.x, lane = t & 63, wid = t >> 6;
    const int nb = blockIdx.x * 2;
#pragma unroll
    for (int i = 0; i < 12; ++i) {
        const int c = wid * 12 + i;
        if (c < 32) {
            const int nn = c >> 4, k = c & 15;
            gload_lds16(xg + (long)(nb + nn) * 8192 + k * 512 + lane * 8,
                        lds + nn * 16384 + k * 1024);
        } else {
            const int cc = c - 32, nn = cc >> 3, k = cc & 7;
            gload_lds16(Wt + (long)(nb + nn) * 4096 + k * 512 + lane * 8,
                        lds + 32768 + nn * 8192 + k * 1024);
        }
    }
    __syncthreads();

    const int ns   = wid >> 1;
    const int node = nb + ns;
    const int bh   = wid & 1;
    const char* xl  = lds + ns * 16384;
    const char* wlp = lds + 32768 + ns * 8192;
    const int p = lane & 15, q = lane >> 4;

    f32x4 acc[4][4];
#pragma unroll
    for (int m = 0; m < 4; ++m)
#pragma unroll
        for (int n = 0; n < 4; ++n) acc[m][n] = f32x4{0.f, 0.f, 0.f, 0.f};

#pragma unroll
    for (int s = 0; s < 2; ++s) {
        const int kb = s * 4 + q;
        bf16x8 a[4], b[4];
#pragma unroll
        for (int m = 0; m < 4; ++m) {
            const int brow = bh * 64 + m * 16 + p;
            a[m] = *(const bf16x8*)(xl + brow * 128 + ((kb ^ (lane & 7)) << 4));
        }
#pragma unroll
        for (int n = 0; n < 4; ++n)
            b[n] = *(const bf16x8*)(wlp + kb * 1024 + (n * 16 + p) * 16);
#pragma unroll
        for (int m = 0; m < 4; ++m)
#pragma unroll
            for (int n = 0; n < 4; ++n)
                acc[m][n] = __builtin_amdgcn_mfma_f32_16x16x32_bf16(a[m], b[n], acc[m][n], 0, 0, 0);
    }

    float bv[4];
#pragma unroll
    for (int n = 0; n < 4; ++n) bv[n] = bias[node * 64 + n * 16 + p];
    __syncthreads();

#pragma unroll
    for (int pass = 0; pass < 2; ++pass) {
        if (bh == pass) {
            char* tb = lds + ns * 17408;
#pragma unroll
            for (int m = 0; m < 4; ++m)
#pragma unroll
                for (int n = 0; n < 4; ++n)
#pragma unroll
                    for (int r = 0; r < 4; ++r) {
                        const int brow = m * 16 + q * 4 + r;
                        *(float*)(tb + brow * 272 + (n * 16 + p) * 4) =
                            acc[m][n][r] + bv[n];
                    }
        }
        __syncthreads();
#pragma unroll
        for (int i = 0; i < 8; ++i) {
            const int idx = i * 256 + t;
            const int tns = idx >> 10, rem = idx & 1023;
            const int b = rem >> 4, g = rem & 15;
            f32x4 v = *(const f32x4*)(lds + tns * 17408 + b * 272 + g * 16);
            *(f32x4*)(out + (long)(pass * 64 + b) * 65536 + (nb + tns) * 64 + g * 4) = v;
        }
        __syncthreads();
    }
}

extern "C" void kernel_launch(void* const* d_in, const int* in_sizes, int n_in,
                              void* d_out, int out_size, void* d_ws, size_t ws_size,
                              hipStream_t stream) {
    const float* x     = (const float*)d_in[0];
    const float* emb   = (const float*)d_in[1];
    const float* wpool = (const float*)d_in[2];
    const float* bpool = (const float*)d_in[3];
    float* out = (float*)d_out;

    char* ws = (char*)d_ws;
    unsigned short* sup  = (unsigned short*)(ws);                        // 2 MiB
    unsigned short* xbt  = (unsigned short*)(ws + (2u  << 20));          // 16 MiB
    unsigned short* Wt   = (unsigned short*)(ws + (18u << 20));          // 8 MiB
    float*          bias = (float*)         (ws + (26u << 20));          // 256 KiB
    unsigned short* xg   = (unsigned short*)(ws + (27u << 20));          // 16 MiB
    (void)in_sizes; (void)n_in; (void)out_size; (void)ws_size;

    k_prep2<<<dim3(3328), dim3(256), 0, stream>>>(x, emb, wpool, bpool,
                                                  xbt, sup, Wt, bias);
    k_agg<<<dim3(256), dim3(512), 0, stream>>>(sup, xbt, xg);
    k_out<<<dim3(512), dim3(256), 0, stream>>>(xg, Wt, bias, out);
}

// Round 20
// 55.457 us; speedup vs baseline: 1.0430x; 1.0206x over previous
//
#include <hip/hip_runtime.h>

#define N_NODES 1024
#define BATCH   128
#define E_DIM   16

// S / xbt panel format (bf16, per 128-row x 1024-k panel, 256KB):
//   elem(row, k) at (k>>6)*8192 + ((k>>3)&7)*1024 + row*8 + (k&7)
// Wt per-node tiled: n*4096 + kblk*512 + o*8 + e   (i = kblk*8+e)
// xg layout (node-major, swizzled): short off =
//   node*8192 + b*64 + ((ib ^ (b&7))*8 + e)   where i = ib*8+e

typedef __attribute__((ext_vector_type(8))) short bf16x8;
typedef __attribute__((ext_vector_type(4))) float f32x4;
typedef __attribute__((ext_vector_type(16))) float f32x16;

__device__ __forceinline__ unsigned short f2bf(float f) {
    union { float f; unsigned int u; } v; v.f = f;
    unsigned int u = v.u;
    u += 0x7FFFu + ((u >> 16) & 1u);
    return (unsigned short)(u >> 16);
}

__device__ __forceinline__ void gload_lds16(const void* g, void* l) {
    __builtin_amdgcn_global_load_lds(
        (const __attribute__((address_space(1))) unsigned int*)g,
        (__attribute__((address_space(3))) unsigned int*)l, 16, 0, 0);
}

// ---------------- P: fused producers (xt | weights-4node | supports) --------
// grid: [0,2048) xt | [2048,2304) weights | [2304,3328) supports
__global__ __launch_bounds__(256) void k_prep2(const float* __restrict__ x,
                                               const float* __restrict__ emb,
                                               const float* __restrict__ wpool,
                                               const float* __restrict__ bpool,
                                               unsigned short* __restrict__ xbt,
                                               unsigned short* __restrict__ sup,
                                               unsigned short* __restrict__ Wt,
                                               float* __restrict__ bias) {
    __shared__ float sm[132];
    const int bid = blockIdx.x;
    const int t = threadIdx.x;

    if (bid < 2048) {
        // ---- xt: register-only transpose, both sides coalesced ----
        const int b = bid >> 4, kt64 = bid & 15;
        unsigned short* dstp = xbt + (long)(b >> 1) * 131072 + kt64 * 8192
                             + (b & 1) * 512;
#pragma unroll
        for (int h = 0; h < 2; ++h) {
            const int g = h * 256 + t;
            const int kblk = g >> 6, c = g & 63;
            const float* s = x + ((long)b * 1024 + kt64 * 64 + kblk * 8) * 64 + c;
            bf16x8 r;
#pragma unroll
            for (int e = 0; e < 8; ++e) r[e] = (short)f2bf(s[e * 64]);
            *(bf16x8*)(dstp + kblk * 1024 + c * 8) = r;
        }
    } else if (bid < 2304) {
        // ---- weights: 4 nodes/block, register-direct ----
        float (*en4)[E_DIM] = (float(*)[E_DIM])sm;
        const int n0 = (bid - 2048) * 4;
        if (t < 64) en4[t >> 4][t & 15] = emb[(n0 + (t >> 4)) * E_DIM + (t & 15)];
        __syncthreads();
        const int o = t & 63;
#pragma unroll
        for (int p = 0; p < 2; ++p) {
            const int kblk = p * 4 + (t >> 6);
            float w[4][8];
#pragma unroll
            for (int nn = 0; nn < 4; ++nn)
#pragma unroll
                for (int e = 0; e < 8; ++e) w[nn][e] = 0.f;
            for (int ed = 0; ed < E_DIM; ++ed) {
                float v[8];
#pragma unroll
                for (int e = 0; e < 8; ++e)
                    v[e] = wpool[ed * 4096 + (kblk * 8 + e) * 64 + o];
#pragma unroll
                for (int nn = 0; nn < 4; ++nn)
#pragma unroll
                    for (int e = 0; e < 8; ++e)
                        w[nn][e] = fmaf(en4[nn][ed], v[e], w[nn][e]);
            }
#pragma unroll
            for (int nn = 0; nn < 4; ++nn) {
                bf16x8 r;
#pragma unroll
                for (int e = 0; e < 8; ++e) r[e] = (short)f2bf(w[nn][e]);
                *(bf16x8*)(Wt + (long)(n0 + nn) * 4096 + kblk * 512 + o * 8) = r;
            }
        }
        {
            const int nn = t >> 6, oo = t & 63;
            float s = 0.f;
#pragma unroll
            for (int e = 0; e < E_DIM; ++e) s = fmaf(en4[nn][e], bpool[e * 64 + oo], s);
            bias[(n0 + nn) * 64 + oo] = s;
        }
    } else {
        // ---- supports: softmax(relu(emb emb^T)) row, tiled ----
        float* en  = sm;
        float* red = sm + 128;
        const int n = bid - 2304;
        if (t < E_DIM) en[t] = emb[n * E_DIM + t];
        __syncthreads();
        float sc[4];
        float mx = -1e30f;
#pragma unroll
        for (int r = 0; r < 4; ++r) {
            const float* em = &emb[(r * 256 + t) * E_DIM];
            float s = 0.f;
#pragma unroll
            for (int e = 0; e < E_DIM; ++e) s = fmaf(en[e], em[e], s);
            s = fmaxf(s, 0.f);
            sc[r] = s;
            mx = fmaxf(mx, s);
        }
#pragma unroll
        for (int o = 32; o > 0; o >>= 1) mx = fmaxf(mx, __shfl_xor(mx, o));
        if ((t & 63) == 0) red[t >> 6] = mx;
        __syncthreads();
        mx = fmaxf(fmaxf(red[0], red[1]), fmaxf(red[2], red[3]));
        float sum = 0.f;
#pragma unroll
        for (int r = 0; r < 4; ++r) { sc[r] = __expf(sc[r] - mx); sum += sc[r]; }
#pragma unroll
        for (int o = 32; o > 0; o >>= 1) sum += __shfl_xor(sum, o);
        __syncthreads();
        if ((t & 63) == 0) red[t >> 6] = sum;
        __syncthreads();
        sum = red[0] + red[1] + red[2] + red[3];
        const float inv = 1.f / sum;
#pragma unroll
        for (int r = 0; r < 4; ++r) {
            const int m = r * 256 + t;
            const int off = (n >> 7) * 131072 + (m >> 6) * 8192 + ((m >> 3) & 7) * 1024
                          + (n & 127) * 8 + (m & 7);
            sup[off] = f2bf(sc[r] * inv);
        }
    }
}

// ---------------- D: xg = S @ X, 128x128, BK=32, 3-buffer pipeline ----------
__global__ __launch_bounds__(256, 3) void k_agg(const unsigned short* __restrict__ S,
                                                const unsigned short* __restrict__ Bt,
                                                unsigned short* __restrict__ xg) {
    __shared__ __align__(16) char lds[49152];   // 3 buffers x 16KB
    const int t = threadIdx.x;
    const int lane = t & 63, wid = t >> 6;

    const int hw   = blockIdx.x + 8 * blockIdx.y;      // grid (8, 64)
    const int work = (hw & 7) * 64 + (hw >> 3);        // XCD-chunked swizzle
    const int n0 = (work & 7) * 128, j0 = (work >> 3) * 128;
    const int wr = wid >> 1, wc = wid & 1;

    f32x16 acc[2][2];
#pragma unroll
    for (int m = 0; m < 2; ++m)
#pragma unroll
        for (int n = 0; n < 2; ++n)
#pragma unroll
            for (int r = 0; r < 16; ++r) acc[m][n][r] = 0.f;

    const unsigned short* pA = S  + (n0 >> 7) * 131072 + lane * 8;
    const unsigned short* pB = Bt + (j0 >> 7) * 131072 + lane * 8;
    const unsigned short* sp[4];
    int doff[4];
#pragma unroll
    for (int i = 0; i < 4; ++i) {
        const int c = wid * 4 + i;
        if (c < 8) { sp[i] = pA + c * 512;       doff[i] = c * 1024; }
        else       { sp[i] = pB + (c - 8) * 512; doff[i] = 8192 + (c - 8) * 1024; }
    }
#define STAGE(bufidx, kt) do {                                           \
        char* buf_ = lds + (bufidx) * 16384;                             \
        const int ko_ = (kt) * 4096;                                     \
        gload_lds16(sp[0] + ko_, buf_ + doff[0]);                        \
        gload_lds16(sp[1] + ko_, buf_ + doff[1]);                        \
        gload_lds16(sp[2] + ko_, buf_ + doff[2]);                        \
        gload_lds16(sp[3] + ko_, buf_ + doff[3]);                        \
    } while (0)

    int aoff[2], boff[2];
#pragma unroll
    for (int m = 0; m < 2; ++m)
        aoff[m] = (lane >> 5) * 2048 + (wr * 64 + m * 32 + (lane & 31)) * 16;
#pragma unroll
    for (int n = 0; n < 2; ++n)
        boff[n] = 8192 + (lane >> 5) * 2048 + (wc * 64 + n * 32 + (lane & 31)) * 16;

    STAGE(0, 0); STAGE(1, 1);
    int bcur = 0;
    for (int kt = 0; kt < 32; ++kt) {
        if (kt < 31) asm volatile("s_waitcnt vmcnt(4)" ::: "memory");
        else         asm volatile("s_waitcnt vmcnt(0)" ::: "memory");
        __builtin_amdgcn_s_barrier();
        asm volatile("" ::: "memory");
        __builtin_amdgcn_sched_barrier(0);
        const int bprev = (bcur + 2 >= 3) ? bcur - 1 : bcur + 2;
        if (kt + 2 < 32) STAGE(bprev, kt + 2);
        const char* cur = lds + bcur * 16384;
        __builtin_amdgcn_s_setprio(1);
#pragma unroll
        for (int s = 0; s < 2; ++s) {
            bf16x8 a[2], b[2];
#pragma unroll
            for (int m = 0; m < 2; ++m) a[m] = *(const bf16x8*)(cur + s * 4096 + aoff[m]);
#pragma unroll
            for (int n = 0; n < 2; ++n) b[n] = *(const bf16x8*)(cur + s * 4096 + boff[n]);
#pragma unroll
            for (int m = 0; m < 2; ++m)
#pragma unroll
                for (int n = 0; n < 2; ++n)
                    acc[m][n] = __builtin_amdgcn_mfma_f32_32x32x16_bf16(a[m], b[n], acc[m][n], 0, 0, 0);
        }
        __builtin_amdgcn_s_setprio(0);
        asm volatile("" ::: "memory");
        __builtin_amdgcn_sched_barrier(0);
        bcur = (bcur + 1 >= 3) ? 0 : bcur + 1;
    }
#undef STAGE
    __syncthreads();

    // epilogue: acc -> LDS bf16 [128 row][128 col] swizzled -> node-major xg
    char* lb = lds;
#pragma unroll
    for (int m = 0; m < 2; ++m) {
#pragma unroll
        for (int n = 0; n < 2; ++n) {
            const int col  = wc * 64 + n * 32 + (lane & 31);
            const int rowb = wr * 64 + m * 32 + 4 * (lane >> 5);
#pragma unroll
            for (int r = 0; r < 16; ++r) {
                const int row = rowb + (r & 3) + 8 * (r >> 2);
                *(unsigned short*)(lb + row * 256 + ((col * 2) ^ ((row & 7) << 4))) =
                    f2bf(acc[m][n][r]);
            }
        }
    }
    __syncthreads();
    const int b0 = j0 >> 6;
#pragma unroll
    for (int i = 0; i < 8; ++i) {
        const int idx = i * 256 + t;
        const int row = idx >> 4, cc = idx & 15;
        bf16x8 v = *(const bf16x8*)(lb + row * 256 + ((cc * 16) ^ ((row & 7) << 4)));
        const int b = b0 + (cc >> 3);
        const long dst = (long)(n0 + row) * 8192 + b * 64 + ((cc & 7) ^ (b & 7)) * 8;
        *(bf16x8*)(xg + dst) = v;
    }
}

// ---------------- E: out, 2 nodes/block, f32x4 staged stores ----------------
__global__ __launch_bounds__(256) void k_out(const unsigned short* __restrict__ xg,
                                             const unsigned short* __restrict__ Wt,
                                             const float* __restrict__ bias,
                                             float* __restrict__ out) {
    __shared__ __align__(16) char lds[49152];
    const int t = threadIdx.x, lane = t & 63, wid = t >> 6;
    const int nb = blockIdx.x * 2;
#pragma unroll
    for (int i = 0; i < 12; ++i) {
        const int c = wid * 12 + i;
        if (c < 32) {
            const int nn = c >> 4, k = c & 15;
            gload_lds16(xg + (long)(nb + nn) * 8192 + k * 512 + lane * 8,
                        lds + nn * 16384 + k * 1024);
        } else {
            const int cc = c - 32, nn = cc >> 3, k = cc & 7;
            gload_lds16(Wt + (long)(nb + nn) * 4096 + k * 512 + lane * 8,
                        lds + 32768 + nn * 8192 + k * 1024);
        }
    }
    __syncthreads();

    const int ns   = wid >> 1;
    const int node = nb + ns;
    const int bh   = wid & 1;
    const char* xl  = lds + ns * 16384;
    const char* wlp = lds + 32768 + ns * 8192;
    const int p = lane & 15, q = lane >> 4;

    f32x4 acc[4][4];
#pragma unroll
    for (int m = 0; m < 4; ++m)
#pragma unroll
        for (int n = 0; n < 4; ++n) acc[m][n] = f32x4{0.f, 0.f, 0.f, 0.f};

#pragma unroll
    for (int s = 0; s < 2; ++s) {
        const int kb = s * 4 + q;
        bf16x8 a[4], b[4];
#pragma unroll
        for (int m = 0; m < 4; ++m) {
            const int brow = bh * 64 + m * 16 + p;
            a[m] = *(const bf16x8*)(xl + brow * 128 + ((kb ^ (lane & 7)) << 4));
        }
#pragma unroll
        for (int n = 0; n < 4; ++n)
            b[n] = *(const bf16x8*)(wlp + kb * 1024 + (n * 16 + p) * 16);
#pragma unroll
        for (int m = 0; m < 4; ++m)
#pragma unroll
            for (int n = 0; n < 4; ++n)
                acc[m][n] = __builtin_amdgcn_mfma_f32_16x16x32_bf16(a[m], b[n], acc[m][n], 0, 0, 0);
    }

    float bv[4];
#pragma unroll
    for (int n = 0; n < 4; ++n) bv[n] = bias[node * 64 + n * 16 + p];
    __syncthreads();

#pragma unroll
    for (int pass = 0; pass < 2; ++pass) {
        if (bh == pass) {
            char* tb = lds + ns * 17408;
#pragma unroll
            for (int m = 0; m < 4; ++m)
#pragma unroll
                for (int n = 0; n < 4; ++n)
#pragma unroll
                    for (int r = 0; r < 4; ++r) {
                        const int brow = m * 16 + q * 4 + r;
                        *(float*)(tb + brow * 272 + (n * 16 + p) * 4) =
                            acc[m][n][r] + bv[n];
                    }
        }
        __syncthreads();
#pragma unroll
        for (int i = 0; i < 8; ++i) {
            const int idx = i * 256 + t;
            const int tns = idx >> 10, rem = idx & 1023;
            const int b = rem >> 4, g = rem & 15;
            f32x4 v = *(const f32x4*)(lds + tns * 17408 + b * 272 + g * 16);
            *(f32x4*)(out + (long)(pass * 64 + b) * 65536 + (nb + tns) * 64 + g * 4) = v;
        }
        __syncthreads();
    }
}

extern "C" void kernel_launch(void* const* d_in, const int* in_sizes, int n_in,
                              void* d_out, int out_size, void* d_ws, size_t ws_size,
                              hipStream_t stream) {
    const float* x     = (const float*)d_in[0];
    const float* emb   = (const float*)d_in[1];
    const float* wpool = (const float*)d_in[2];
    const float* bpool = (const float*)d_in[3];
    float* out = (float*)d_out;

    char* ws = (char*)d_ws;
    unsigned short* sup  = (unsigned short*)(ws);                        // 2 MiB
    unsigned short* xbt  = (unsigned short*)(ws + (2u  << 20));          // 16 MiB
    unsigned short* Wt   = (unsigned short*)(ws + (18u << 20));          // 8 MiB
    float*          bias = (float*)         (ws + (26u << 20));          // 256 KiB
    unsigned short* xg   = (unsigned short*)(ws + (27u << 20));          // 16 MiB
    (void)in_sizes; (void)n_in; (void)out_size; (void)ws_size;

    k_prep2<<<dim3(3328), dim3(256), 0, stream>>>(x, emb, wpool, bpool,
                                                  xbt, sup, Wt, bias);
    k_agg<<<dim3(8, 64), dim3(256), 0, stream>>>(sup, xbt, xg);
    k_out<<<dim3(512), dim3(256), 0, stream>>>(xg, Wt, bias, out);
}